// Round 7
// baseline (123.078 us; speedup 1.0000x reference)
//
#include <hip/hip_runtime.h>

#define BB 64
#define NN 512
#define DD 3
#define EPSF 1e-7f
#define SPLIT 64               // blocks per sample in x
#define NBLK (BB * SPLIT)      // 4096 blocks total

// ws (floats):
//   [0 .. NBLK)        edge BCE partial per (b, x)  -- written unconditionally by every block
//   [NBLK .. +BB)      n per sample                 -- written by (0, b)
//   [NBLK+BB .. +2BB)  coord SE per sample          -- written by (0, b)
//   [NBLK+2BB]         ticket counter (uint32)      -- memset to 0 each launch
#define WS_EDGE 0
#define WS_N    NBLK
#define WS_SE   (NBLK + BB)
#define WS_CNT  (NBLK + 2 * BB)

__global__ __launch_bounds__(256) void fused_kernel(const float* __restrict__ am,
                                                    const float* __restrict__ adj,
                                                    const float* __restrict__ pc,
                                                    const float* __restrict__ pts,
                                                    const int* __restrict__ masks,
                                                    const float* __restrict__ counts,
                                                    float* __restrict__ ws,
                                                    float* __restrict__ out) {
    const int bx  = blockIdx.x;
    const int b   = blockIdx.y;
    const int tid = threadIdx.x;
    const int wid  = tid >> 6;
    const int lane = tid & 63;

    __shared__ float s_part[4];
    __shared__ float s_cpart[4];
    __shared__ int   s_cnt4[4];
    __shared__ int   s_win;

    // ---- n = popcount of prefix mask via 2 ballots per wave ----
    const int2 mv = ((const int2*)(masks + b * NN))[tid];   // positions 2tid, 2tid+1
    const unsigned long long bx_ = __ballot(mv.x != 0);
    const unsigned long long by_ = __ballot(mv.y != 0);
    if (lane == 0) s_cnt4[wid] = __popcll(bx_) + __popcll(by_);
    __syncthreads();
    const int n = s_cnt4[0] + s_cnt4[1] + s_cnt4[2] + s_cnt4[3];

    // ---- coord SE (bx==0 blocks only) ----
    if (bx == 0) {
        const float* pcb = pc  + b * (NN * DD);
        const float* ptb = pts + b * (NN * DD);
        float se = 0.f;
        for (int e = tid; e < NN * DD; e += 256) {
            if (e < n * DD) {                 // prefix mask: element valid iff e < n*DD
                const float d = pcb[e] - ptb[e];
                se += d * d;
            }
        }
#pragma unroll
        for (int off = 32; off; off >>= 1) se += __shfl_xor(se, off);
        if (lane == 0) s_cpart[wid] = se;
    }

    // ---- edge BCE partial: 2 half-waves each cover one row's 512 floats ----
    const int half    = tid >> 7;
    const int lane128 = tid & 127;
    const int j0      = lane128 * 4;
    float sum = 0.f;
    if (j0 < n) {
        const size_t bbase = (size_t)b * NN * NN;
        for (int row = bx + half * SPLIT; row < n; row += 2 * SPLIT) {
            const float4 p4 = *(const float4*)(am  + bbase + (size_t)row * NN + j0);
            const float4 a4 = *(const float4*)(adj + bbase + (size_t)row * NN + j0);
            const float pv[4] = {p4.x, p4.y, p4.z, p4.w};
            const float av[4] = {a4.x, a4.y, a4.z, a4.w};
#pragma unroll
            for (int k = 0; k < 4; ++k) {
                if (j0 + k < n) {
                    // a ∈ {0,1}: bce = -log(clamp(a ? p : 1-p)); 1-clamp(p) == clamp(1-p)
                    const float r = (av[k] != 0.f) ? pv[k] : 1.f - pv[k];
                    const float q = fminf(fmaxf(r, EPSF), 1.f - EPSF);
                    sum -= __logf(q);
                }
            }
        }
    }
#pragma unroll
    for (int off = 32; off; off >>= 1) sum += __shfl_xor(sum, off);
    if (lane == 0) s_part[wid] = sum;
    __syncthreads();

    // ---- publish partials, take a ticket; last block finalizes ----
    if (tid == 0) {
        ws[WS_EDGE + b * SPLIT + bx] = s_part[0] + s_part[1] + s_part[2] + s_part[3];
        if (bx == 0) {
            ws[WS_N + b]  = (float)n;
            ws[WS_SE + b] = s_cpart[0] + s_cpart[1] + s_cpart[2] + s_cpart[3];
        }
        __threadfence();                                   // device-scope release
        const unsigned old = atomicAdd((unsigned*)(ws + WS_CNT), 1u);
        s_win = (old == NBLK - 1) ? 1 : 0;
    }
    __syncthreads();
    if (!s_win) return;
    __threadfence();                                       // device-scope acquire

    // ---- final reduction (winner block, lanes 0..63 = wave 0) ----
    if (tid < BB) {
        const float4* ep = (const float4*)(ws + WS_EDGE + tid * SPLIT);
        float es = 0.f;
#pragma unroll
        for (int k = 0; k < SPLIT / 4; ++k) {
            const float4 v = ep[k];
            es += v.x + v.y + v.z + v.w;
        }
        const float nf = ws[WS_N + tid];
        const float se = ws[WS_SE + tid];

        const float coord_b = se / fmaxf(nf * (float)DD, 1.f);
        const float edge_b  = es / fmaxf(nf * nf, 1.f);
        const float valid   = (nf > 0.f) ? 1.f : 0.f;
        const float dc      = counts[tid] - nf;

        float v0 = valid;
        float v1 = coord_b * valid;
        float v2 = edge_b * valid;
        float v3 = dc * dc;
#pragma unroll
        for (int off = 32; off > 0; off >>= 1) {
            v0 += __shfl_down(v0, off);
            v1 += __shfl_down(v1, off);
            v2 += __shfl_down(v2, off);
            v3 += __shfl_down(v3, off);
        }
        if (tid == 0) {
            const float vc = v0;
            const float denom = fmaxf(vc, 1.f);
            const float coord_loss = (vc > 0.f) ? (v1 / denom) : 0.f;
            const float edge_loss  = (vc > 0.f) ? (v2 / denom) : 0.f;
            const float count_loss = v3 / (float)BB;
            out[0] = coord_loss + edge_loss + 0.1f * count_loss;  // total
            out[1] = coord_loss;
            out[2] = edge_loss;
            out[3] = count_loss;
        }
    }
}

extern "C" void kernel_launch(void* const* d_in, const int* in_sizes, int n_in,
                              void* d_out, int out_size, void* d_ws, size_t ws_size,
                              hipStream_t stream) {
    const float* pc    = (const float*)d_in[0];  // predicted_coords [B,N,D]
    const float* am    = (const float*)d_in[1];  // adjacency_matrix [B,N,N]
    const float* nc    = (const float*)d_in[2];  // node_counts [B,1]
    const float* pts   = (const float*)d_in[3];  // points [B,N,D]
    const float* adj   = (const float*)d_in[4];  // adjacency [B,N,N]
    const int*   masks = (const int*)d_in[5];    // node_masks [B,N]
    float* ws  = (float*)d_ws;
    float* out = (float*)d_out;

    // zero the ticket counter (graph-capturable memset node)
    hipMemsetAsync(ws + WS_CNT, 0, sizeof(unsigned), stream);

    dim3 grid(SPLIT, BB);
    fused_kernel<<<grid, 256, 0, stream>>>(am, adj, pc, pts, masks, nc, ws, out);
}

// Round 8
// 21.544 us; speedup vs baseline: 5.7128x; 5.7128x over previous
//
#include <hip/hip_runtime.h>

#define BB 64
#define NN 512
#define DD 3
#define EPSF 1e-7f
#define SPLIT 32               // blocks per sample in x; 2048 blocks total
#define NBLK (BB * SPLIT)

// ws (floats):
//   [0 .. NBLK)        edge BCE partial per (b, x)  -- written unconditionally by every block
//   [NBLK .. +BB)      n per sample                 -- written by (0, b)
//   [NBLK+BB .. +2BB)  coord SE per sample          -- written by (0, b)
#define WS_EDGE 0
#define WS_N    NBLK
#define WS_SE   (NBLK + BB)

__global__ __launch_bounds__(256) void fused_kernel(const float* __restrict__ am,
                                                    const float* __restrict__ adj,
                                                    const float* __restrict__ pc,
                                                    const float* __restrict__ pts,
                                                    const int* __restrict__ masks,
                                                    float* __restrict__ ws) {
    const int bx  = blockIdx.x;
    const int b   = blockIdx.y;
    const int tid = threadIdx.x;
    const int wid  = tid >> 6;
    const int lane = tid & 63;
    const int half    = tid >> 7;        // 0 or 1
    const int lane128 = tid & 127;
    const int j0      = lane128 * 4;

    __shared__ int   s_cnt4[4];
    __shared__ float s_part[4];
    __shared__ float s_cpart[4];

    // ---- prefetch first row pair BEFORE the mask read (always in-bounds:
    //      row0 < 2*SPLIT <= NN); overlaps the two cold-miss latencies ----
    const size_t bbase = (size_t)b * NN * NN;
    const int row0 = bx + half * SPLIT;
    const float4 p0 = *(const float4*)(am  + bbase + (size_t)row0 * NN + j0);
    const float4 a0 = *(const float4*)(adj + bbase + (size_t)row0 * NN + j0);

    // ---- n = popcount of prefix mask via 2 ballots per wave ----
    const int2 mv = ((const int2*)(masks + b * NN))[tid];   // positions 2tid, 2tid+1
    const unsigned long long bl0 = __ballot(mv.x != 0);
    const unsigned long long bl1 = __ballot(mv.y != 0);
    if (lane == 0) s_cnt4[wid] = __popcll(bl0) + __popcll(bl1);
    __syncthreads();
    const int n = s_cnt4[0] + s_cnt4[1] + s_cnt4[2] + s_cnt4[3];

    // ---- coord SE (bx==0 blocks only) ----
    if (bx == 0) {
        const float* pcb = pc  + b * (NN * DD);
        const float* ptb = pts + b * (NN * DD);
        float se = 0.f;
        for (int e = tid; e < NN * DD; e += 256) {
            if (e < n * DD) {                 // prefix mask: element valid iff e < n*DD
                const float d = pcb[e] - ptb[e];
                se += d * d;
            }
        }
#pragma unroll
        for (int off = 32; off; off >>= 1) se += __shfl_xor(se, off);
        if (lane == 0) s_cpart[wid] = se;
    }

    // ---- edge BCE partial: 2 half-waves; rows row0, row0+64, ... < n ----
    float sum = 0.f;
    if (row0 < n && j0 < n) {               // consume the prefetched first row
        const float pv[4] = {p0.x, p0.y, p0.z, p0.w};
        const float av[4] = {a0.x, a0.y, a0.z, a0.w};
#pragma unroll
        for (int k = 0; k < 4; ++k) {
            if (j0 + k < n) {
                // a ∈ {0,1}: bce = -log(clamp(a ? p : 1-p)); 1-clamp(p) == clamp(1-p)
                const float r = (av[k] != 0.f) ? pv[k] : 1.f - pv[k];
                const float q = fminf(fmaxf(r, EPSF), 1.f - EPSF);
                sum -= __logf(q);
            }
        }
    }
    if (j0 < n) {
#pragma unroll 2
        for (int row = row0 + 2 * SPLIT; row < n; row += 2 * SPLIT) {
            const float4 p4 = *(const float4*)(am  + bbase + (size_t)row * NN + j0);
            const float4 a4 = *(const float4*)(adj + bbase + (size_t)row * NN + j0);
            const float pv[4] = {p4.x, p4.y, p4.z, p4.w};
            const float av[4] = {a4.x, a4.y, a4.z, a4.w};
#pragma unroll
            for (int k = 0; k < 4; ++k) {
                if (j0 + k < n) {
                    const float r = (av[k] != 0.f) ? pv[k] : 1.f - pv[k];
                    const float q = fminf(fmaxf(r, EPSF), 1.f - EPSF);
                    sum -= __logf(q);
                }
            }
        }
    }
#pragma unroll
    for (int off = 32; off; off >>= 1) sum += __shfl_xor(sum, off);
    if (lane == 0) s_part[wid] = sum;
    __syncthreads();

    if (tid == 0) {
        ws[WS_EDGE + b * SPLIT + bx] = s_part[0] + s_part[1] + s_part[2] + s_part[3];
        if (bx == 0) {
            ws[WS_N + b]  = (float)n;
            ws[WS_SE + b] = s_cpart[0] + s_cpart[1] + s_cpart[2] + s_cpart[3];
        }
    }
}

__global__ __launch_bounds__(64) void final_kernel(const float* __restrict__ ws,
                                                   const float* __restrict__ counts,
                                                   float* __restrict__ out) {
    const int b = threadIdx.x;   // 64 threads == B samples

    // sum this sample's SPLIT edge partials (8 x float4)
    const float4* ep = (const float4*)(ws + WS_EDGE + b * SPLIT);
    float es = 0.f;
#pragma unroll
    for (int k = 0; k < SPLIT / 4; ++k) {
        const float4 v = ep[k];
        es += v.x + v.y + v.z + v.w;
    }

    const float n  = ws[WS_N + b];
    const float se = ws[WS_SE + b];

    const float coord_b = se / fmaxf(n * (float)DD, 1.f);
    const float edge_b  = es / fmaxf(n * n, 1.f);
    const float valid   = (n > 0.f) ? 1.f : 0.f;
    const float dc      = counts[b] - n;

    float v0 = valid;
    float v1 = coord_b * valid;
    float v2 = edge_b * valid;
    float v3 = dc * dc;
#pragma unroll
    for (int off = 32; off > 0; off >>= 1) {
        v0 += __shfl_down(v0, off);
        v1 += __shfl_down(v1, off);
        v2 += __shfl_down(v2, off);
        v3 += __shfl_down(v3, off);
    }
    if (b == 0) {
        const float vc = v0;
        const float denom = fmaxf(vc, 1.f);
        const float coord_loss = (vc > 0.f) ? (v1 / denom) : 0.f;
        const float edge_loss  = (vc > 0.f) ? (v2 / denom) : 0.f;
        const float count_loss = v3 / (float)BB;
        out[0] = coord_loss + edge_loss + 0.1f * count_loss;  // total
        out[1] = coord_loss;
        out[2] = edge_loss;
        out[3] = count_loss;
    }
}

extern "C" void kernel_launch(void* const* d_in, const int* in_sizes, int n_in,
                              void* d_out, int out_size, void* d_ws, size_t ws_size,
                              hipStream_t stream) {
    const float* pc    = (const float*)d_in[0];  // predicted_coords [B,N,D]
    const float* am    = (const float*)d_in[1];  // adjacency_matrix [B,N,N]
    const float* nc    = (const float*)d_in[2];  // node_counts [B,1]
    const float* pts   = (const float*)d_in[3];  // points [B,N,D]
    const float* adj   = (const float*)d_in[4];  // adjacency [B,N,N]
    const int*   masks = (const int*)d_in[5];    // node_masks [B,N]
    float* ws  = (float*)d_ws;
    float* out = (float*)d_out;

    dim3 grid(SPLIT, BB);
    fused_kernel<<<grid, 256, 0, stream>>>(am, adj, pc, pts, masks, ws);
    final_kernel<<<1, 64, 0, stream>>>(ws, nc, out);
}